// Round 17
// baseline (139.964 us; speedup 1.0000x reference)
//
#include <hip/hip_runtime.h>

typedef short short8 __attribute__((ext_vector_type(8)));
typedef float floatx4 __attribute__((ext_vector_type(4)));
typedef unsigned uint2v __attribute__((ext_vector_type(2)));

#define INF 4096
#define TROWS 32
#define RS 528              // bf16 row stride: 512 B data + 16 B pad
#define TB (TROWS * RS)     // 16,896 B per buffer

// fp32 -> bf16 round-to-nearest-even (W prologue only)
__device__ __forceinline__ ushort f2bf(float f) {
  unsigned u = __builtin_bit_cast(unsigned, f);
  u += 0x7fffu + ((u >> 16) & 1u);
  return (ushort)(u >> 16);
}

// Block-diagonal GEMM v17 = v10's schedule in TWO barrier domains per CU.
// Ledger: v10=108.5us; load-depth (v13/14/15), store-defer (v16) all null ->
// the residual (~22% off copy ceiling) is not load- or store-side scheduling.
// Last untested cell: rendezvous skew -- v10's single 8-wave barrier domain
// serializes the whole CU to the slowest wave each tile (co-residency was only
// ever tested WITH vmcnt(0) drains in r4-6). v17: 256-thr WGs (4 waves), grid
// 512 = 16 kb x 32 mg (512 rows = 16 tiles of 32); per-CU work/traffic/LDS
// identical to v10, but 2 WGs/CU rendezvous independently -- while WG A syncs,
// WG B issues. Wave width doubles (64 out-cols: wf[4][8]; 8 staged rows; 64
// MFMA/tile) so per-CU totals match v10 exactly. All waits compiler-managed
// (spill-safe); raw s_barrier + lgkmcnt(0) only, loads cross barriers freely.
// W_k in regs, swapped mfma(W,x)->D[n][m], dwordx4 coalesced IO.
__global__ __launch_bounds__(256, 2) void bd_gemm(
    const float* __restrict__ x, const float* __restrict__ W,
    const float* __restrict__ bias, float* __restrict__ out)
{
  __shared__ __align__(16) char xlds[2 * TB];  // 33,792 B per WG

  const int bid  = blockIdx.x;
  const int kb   = bid & 15;   // xcd = bid%8 -> 2 k-blocks per XCD: W L2-resident
  const int mg   = bid >> 4;   // 0..31, 512 rows each
  const int tid  = threadIdx.x;
  const int lane = tid & 63;
  const int w    = tid >> 6;   // wave 0..3 -> out-col slice of 64
  const int ln   = lane & 15;
  const int lk   = lane >> 4;  // 0..3

  const float* xbase = x   + (size_t)(mg * 512) * INF + kb * 256;
  float*       obase = out + (size_t)(mg * 512) * INF + kb * 256 + w * 64;

#define LGKM0_BAR()                                                           \
  do {                                                                        \
    asm volatile("s_waitcnt lgkmcnt(0)" ::: "memory");                        \
    __builtin_amdgcn_s_barrier();                                             \
    asm volatile("" ::: "memory");                                            \
  } while (0)

  floatx4 g[8];  // staging: 8 rows/wave/tile, 16 B/lane (32 VGPR)

  // one instruction = one contiguous 1 KB fp32 row -> regs
#define LOADX(t)                                                              \
  _Pragma("unroll") for (int i_ = 0; i_ < 8; ++i_)                            \
    g[i_] = *(const floatx4*)(xbase + (size_t)((t) * TROWS + w * 8 + i_) * INF + lane * 4);

  // cvt ONCE to bf16, ds_write_b64: row r gets bytes [lane*8, lane*8+8)
#define WRITEX(t)                                                             \
  _Pragma("unroll") for (int i_ = 0; i_ < 8; ++i_) {                          \
    const int r_ = w * 8 + i_;                                                \
    unsigned p0_, p1_;                                                        \
    asm("v_cvt_pk_bf16_f32 %0, %1, %2" : "=v"(p0_) : "v"(g[i_][0]), "v"(g[i_][1])); \
    asm("v_cvt_pk_bf16_f32 %0, %1, %2" : "=v"(p1_) : "v"(g[i_][2]), "v"(g[i_][3])); \
    uint2v u_; u_[0] = p0_; u_[1] = p1_;                                      \
    *(uint2v*)(xlds + ((t) & 1) * TB + r_ * RS + lane * 8) = u_;              \
  }

  // 16 ds_read_b128 + 64 MFMA per tile per wave (frag: x[mi*16+ln][kc*32+lk*8+e])
#define COMPUTE(t)                                                            \
  {                                                                           \
    const char* bb_ = xlds + ((t) & 1) * TB;                                  \
    _Pragma("unroll") for (int a_ = 0; a_ < 8; ++a_)                          \
      _Pragma("unroll") for (int e_ = 0; e_ < 4; ++e_) acc[a_][e_] = 0.0f;    \
    _Pragma("unroll") for (int kc_ = 0; kc_ < 8; ++kc_) {                     \
      short8 xf_[2];                                                          \
      _Pragma("unroll") for (int mi_ = 0; mi_ < 2; ++mi_)                     \
        xf_[mi_] = *(const short8*)(bb_ + (mi_ * 16 + ln) * RS + kc_ * 64 + lk * 16); \
      _Pragma("unroll") for (int mi_ = 0; mi_ < 2; ++mi_)                     \
        _Pragma("unroll") for (int ni_ = 0; ni_ < 4; ++ni_)                   \
          acc[mi_ * 4 + ni_] = __builtin_amdgcn_mfma_f32_16x16x32_bf16(       \
              wf[ni_][kc_], xf_[mi_], acc[mi_ * 4 + ni_], 0, 0, 0);           \
    }                                                                         \
  }

  // frag D[n][m]: m(row) = mi*16 + ln, n(col) = ni*16 + lk*4 + j -> dwordx4
#define STOREACC(t)                                                           \
  _Pragma("unroll") for (int mi_ = 0; mi_ < 2; ++mi_)                         \
    _Pragma("unroll") for (int ni_ = 0; ni_ < 4; ++ni_) {                     \
      floatx4 r_ = acc[mi_ * 4 + ni_];                                        \
      _Pragma("unroll") for (int j_ = 0; j_ < 4; ++j_) r_[j_] += bv[ni_][j_]; \
      *(floatx4*)(obase + (size_t)((t) * TROWS + mi_ * 16 + ln) * INF +       \
                  ni_ * 16 + lk * 4) = r_;                                    \
    }

  // ---- prologue: tile-0 loads first, W frags under their latency ----
  LOADX(0)

  short8 wf[4][8];  // wave w cols [w*64, w*64+64): A-layout [row=n (ln)][k=lk*8+e]
  {
    const float* wp = W + (size_t)kb * 65536 + (w * 64 + ln) * 256 + lk * 8;
#pragma unroll
    for (int ni = 0; ni < 4; ++ni)
#pragma unroll
      for (int kc = 0; kc < 8; ++kc) {
        const float* s = wp + ni * 16 * 256 + kc * 32;
        floatx4 v0 = *(const floatx4*)s;
        floatx4 v1 = *(const floatx4*)(s + 4);
        short8 u;
#pragma unroll
        for (int j = 0; j < 4; ++j) {
          u[j]     = (short)f2bf(v0[j]);
          u[4 + j] = (short)f2bf(v1[j]);
        }
        wf[ni][kc] = u;
      }
  }
  floatx4 bv[4];
#pragma unroll
  for (int ni = 0; ni < 4; ++ni)
    bv[ni] = *(const floatx4*)(bias + kb * 256 + w * 64 + ni * 16 + lk * 4);

  floatx4 acc[8];

  WRITEX(0)        // compiler's vmcnt wait for g sits here (after W prologue)
  LGKM0_BAR();

  // ---- main loop: 16 tiles of 32 rows, 1 barrier/tile, loads cross barriers --
#pragma unroll 1
  for (int t = 0; t < 16; ++t) {
    if (t < 15) LOADX(t + 1)   // issue next rows; vmcnt wait lands in WRITEX
    COMPUTE(t)
    STOREACC(t)
    if (t < 15) {
      WRITEX(t + 1)            // cvt once; ds_write bf16 into buf (t+1)&1
      LGKM0_BAR();             // ds_writes visible; NO vmcnt drain
    }
  }

#undef LGKM0_BAR
#undef LOADX
#undef WRITEX
#undef COMPUTE
#undef STOREACC
}

extern "C" void kernel_launch(void* const* d_in, const int* in_sizes, int n_in,
                              void* d_out, int out_size, void* d_ws, size_t ws_size,
                              hipStream_t stream) {
  const float* x = (const float*)d_in[0];
  const float* W = (const float*)d_in[1];
  const float* b = (const float*)d_in[2];
  float* out = (float*)d_out;
  // 16 k-blocks x 32 m-groups = 512 WGs (2/CU, independent barrier domains),
  // 256 threads (4 waves) each
  hipLaunchKernelGGL(bd_gemm, dim3(512), dim3(256), 0, stream, x, W, b, out);
}

// Round 19
// 122.939 us; speedup vs baseline: 1.1385x; 1.1385x over previous
//
#include <hip/hip_runtime.h>

typedef short short8 __attribute__((ext_vector_type(8)));
typedef float floatx4 __attribute__((ext_vector_type(4)));
typedef unsigned uint2v __attribute__((ext_vector_type(2)));

#define INF 4096
#define TROWS 32
#define RS 528              // bf16 row stride: 512 B data + 16 B pad
#define TB (TROWS * RS)     // 16,896 B per buffer

// fp32 -> bf16 round-to-nearest-even (W prologue only)
__device__ __forceinline__ ushort f2bf(float f) {
  unsigned u = __builtin_bit_cast(unsigned, f);
  u += 0x7fffu + ((u >> 16) & 1u);
  return (ushort)(u >> 16);
}

// Block-diagonal GEMM v19 = v10 UNCHANGED, grid 256 -> 512 (2 WG/CU).
// v18 (frag-direct, no LDS) failed + had round-2's scatter pattern; dropped.
// v17's co-residency test was confounded (4-wave WGs forced 128-VGPR wf ->
// spill). v10 itself fits 2 WGs/CU: 92 arch + 16 acc VGPR <= 128 (4 waves/
// SIMD), 2 x 33.8 KB LDS <= 160 KB. v19 tests rendezvous-skew cleanly: same
// 8-wave schedule, but two independent barrier domains per CU -- while WG A
// syncs, WG B issues; per-CU in-flight doubles to 64 KB. launch_bounds(512,2)
// calibrated vs round-4 measurement (arg2 ~ WGs/CU: 4 -> cap 64; 2 -> cap 128,
// above the ~108 needed -> no spill).
// Structure (proven, v10): bf16-in-LDS cvt-once; 2 LDS bufs; 1 raw s_barrier
// + lgkmcnt(0) per tile; NO vmcnt drains (staging loads cross barriers);
// compiler-managed vmcnt (spill-robust); W_k in regs (wave w owns out-cols
// [w*32,w*32+32)); swapped mfma(W,x)->D[n][m]; dwordx4 coalesced IO.
// Grid 512 = 16 kb x 32 mg (512 rows = 16 tiles of 32); 512 thr, 2 WG/CU.
__global__ __launch_bounds__(512, 2) void bd_gemm(
    const float* __restrict__ x, const float* __restrict__ W,
    const float* __restrict__ bias, float* __restrict__ out)
{
  __shared__ __align__(16) char xlds[2 * TB];  // 33,792 B

  const int bid  = blockIdx.x;
  const int kb   = bid & 15;   // CU c hosts bids {c, c+256}: same kb -> W L2/L1-warm
  const int mg   = bid >> 4;   // 0..31, 512 rows each
  const int tid  = threadIdx.x;
  const int lane = tid & 63;
  const int w    = tid >> 6;   // wave 0..7 -> out-col slice of 32
  const int ln   = lane & 15;
  const int lk   = lane >> 4;  // 0..3

  const float* xbase = x   + (size_t)(mg * 512) * INF + kb * 256;
  float*       obase = out + (size_t)(mg * 512) * INF + kb * 256 + w * 32;

#define LGKM0_BAR()                                                           \
  do {                                                                        \
    asm volatile("s_waitcnt lgkmcnt(0)" ::: "memory");                        \
    __builtin_amdgcn_s_barrier();                                             \
    asm volatile("" ::: "memory");                                            \
  } while (0)

  floatx4 g[4];  // staging: 4 rows/wave/tile, 16 B/lane (16 VGPR)

  // one instruction = one contiguous 1 KB fp32 row -> regs
#define LOADX(t)                                                              \
  _Pragma("unroll") for (int i_ = 0; i_ < 4; ++i_)                            \
    g[i_] = *(const floatx4*)(xbase + (size_t)((t) * TROWS + w * 4 + i_) * INF + lane * 4);

  // cvt ONCE to bf16, ds_write_b64: row r gets bytes [lane*8, lane*8+8)
#define WRITEX(t)                                                             \
  _Pragma("unroll") for (int i_ = 0; i_ < 4; ++i_) {                          \
    const int r_ = w * 4 + i_;                                                \
    unsigned p0_, p1_;                                                        \
    asm("v_cvt_pk_bf16_f32 %0, %1, %2" : "=v"(p0_) : "v"(g[i_][0]), "v"(g[i_][1])); \
    asm("v_cvt_pk_bf16_f32 %0, %1, %2" : "=v"(p1_) : "v"(g[i_][2]), "v"(g[i_][3])); \
    uint2v u_; u_[0] = p0_; u_[1] = p1_;                                      \
    *(uint2v*)(xlds + ((t) & 1) * TB + r_ * RS + lane * 8) = u_;              \
  }

  // 16 ds_read_b128 + 32 MFMA per tile per wave (frag: x[mi*16+ln][kc*32+lk*8+e])
#define COMPUTE(t)                                                            \
  {                                                                           \
    const char* bb_ = xlds + ((t) & 1) * TB;                                  \
    _Pragma("unroll") for (int a_ = 0; a_ < 4; ++a_)                          \
      _Pragma("unroll") for (int e_ = 0; e_ < 4; ++e_) acc[a_][e_] = 0.0f;    \
    _Pragma("unroll") for (int kc_ = 0; kc_ < 8; ++kc_) {                     \
      short8 xf_[2];                                                          \
      _Pragma("unroll") for (int mi_ = 0; mi_ < 2; ++mi_)                     \
        xf_[mi_] = *(const short8*)(bb_ + (mi_ * 16 + ln) * RS + kc_ * 64 + lk * 16); \
      _Pragma("unroll") for (int mi_ = 0; mi_ < 2; ++mi_)                     \
        _Pragma("unroll") for (int ni_ = 0; ni_ < 2; ++ni_)                   \
          acc[mi_ * 2 + ni_] = __builtin_amdgcn_mfma_f32_16x16x32_bf16(       \
              wf[ni_][kc_], xf_[mi_], acc[mi_ * 2 + ni_], 0, 0, 0);           \
    }                                                                         \
  }

  // frag D[n][m]: m(row) = mi*16 + ln, n(col) = ni*16 + lk*4 + j -> dwordx4
#define STOREACC(t)                                                           \
  _Pragma("unroll") for (int mi_ = 0; mi_ < 2; ++mi_)                         \
    _Pragma("unroll") for (int ni_ = 0; ni_ < 2; ++ni_) {                     \
      floatx4 r_ = acc[mi_ * 2 + ni_];                                        \
      _Pragma("unroll") for (int j_ = 0; j_ < 4; ++j_) r_[j_] += bv[ni_][j_]; \
      *(floatx4*)(obase + (size_t)((t) * TROWS + mi_ * 16 + ln) * INF +       \
                  ni_ * 16 + lk * 4) = r_;                                    \
    }

  // ---- prologue: tile-0 loads first, W frags under their latency ----
  LOADX(0)

  short8 wf[2][8];  // wave w cols [w*32, w*32+32): A-layout [row=n (ln)][k=lk*8+e]
  {
    const float* wp = W + (size_t)kb * 65536 + (w * 32 + ln) * 256 + lk * 8;
#pragma unroll
    for (int ni = 0; ni < 2; ++ni)
#pragma unroll
      for (int kc = 0; kc < 8; ++kc) {
        const float* s = wp + ni * 16 * 256 + kc * 32;
        floatx4 v0 = *(const floatx4*)s;
        floatx4 v1 = *(const floatx4*)(s + 4);
        short8 u;
#pragma unroll
        for (int j = 0; j < 4; ++j) {
          u[j]     = (short)f2bf(v0[j]);
          u[4 + j] = (short)f2bf(v1[j]);
        }
        wf[ni][kc] = u;
      }
  }
  floatx4 bv[2];
#pragma unroll
  for (int ni = 0; ni < 2; ++ni)
    bv[ni] = *(const floatx4*)(bias + kb * 256 + w * 32 + ni * 16 + lk * 4);

  floatx4 acc[4];

  WRITEX(0)        // compiler's vmcnt wait for g sits here (after W prologue)
  LGKM0_BAR();

  // ---- main loop: 16 tiles of 32 rows, 1 barrier/tile, loads cross barriers --
#pragma unroll 1
  for (int t = 0; t < 16; ++t) {
    if (t < 15) LOADX(t + 1)   // issue next rows; vmcnt wait lands in WRITEX
    COMPUTE(t)
    STOREACC(t)
    if (t < 15) {
      WRITEX(t + 1)            // cvt once; ds_write bf16 into buf (t+1)&1
      LGKM0_BAR();             // ds_writes visible; NO vmcnt drain
    }
  }

#undef LGKM0_BAR
#undef LOADX
#undef WRITEX
#undef COMPUTE
#undef STOREACC
}

extern "C" void kernel_launch(void* const* d_in, const int* in_sizes, int n_in,
                              void* d_out, int out_size, void* d_ws, size_t ws_size,
                              hipStream_t stream) {
  const float* x = (const float*)d_in[0];
  const float* W = (const float*)d_in[1];
  const float* b = (const float*)d_in[2];
  float* out = (float*)d_out;
  // 16 k-blocks x 32 m-groups = 512 WGs (2/CU, independent 8-wave barrier
  // domains), 512 threads each
  hipLaunchKernelGGL(bd_gemm, dim3(512), dim3(512), 0, stream, x, W, b, out);
}